// Round 2
// baseline (733.842 us; speedup 1.0000x reference)
//
#include <hip/hip_runtime.h>
#include <stdint.h>

typedef short bf16x8 __attribute__((ext_vector_type(8)));
typedef float f32x4  __attribute__((ext_vector_type(4)));

constexpr int BT = 4096;   // tokens
constexpr int DD = 1024;   // model dim
constexpr int OO = 1024;   // output dim
constexpr int EE = 8;      // experts
constexpr int HH = 4096;   // hidden dim
constexpr int SLOTS = 2 * BT;  // 8192

// ---- pipelined-GEMM geometry: 256x256 tile, BK=32, ring-4 ----
constexpr int BM = 256, BN = 256, BK = 32;
constexpr int RING = 4;
constexpr int A_USH = BM * BK;             // 8192 ushorts (16 KB)
constexpr int SLOT_USH = (BM + BN) * BK;   // 16384 ushorts (32 KB)
constexpr int MAXT = 40;                   // max 256-row m-tiles

__device__ __forceinline__ unsigned short f2bf(float f) {
  unsigned u = __float_as_uint(f);
  u += 0x7fffu + ((u >> 16) & 1u);   // round-to-nearest-even
  return (unsigned short)(u >> 16);
}

// async 16B global->LDS. LDS dest is wave-uniform base; HW adds lane*16.
__device__ __forceinline__ void glds16(const unsigned short* g, unsigned short* l) {
  __builtin_amdgcn_global_load_lds(
      (const __attribute__((address_space(1))) void*)g,
      (__attribute__((address_space(3))) void*)l, 16, 0, 0);
}

// ---------- router: logits, top-2 softmax, expert lists; also x -> bf16 ----------
__global__ __launch_bounds__(256) void router_k(const float* __restrict__ x,
                                                const float* __restrict__ gw,
                                                const float* __restrict__ gb,
                                                unsigned short* __restrict__ xb,
                                                int* __restrict__ cnt,
                                                int* __restrict__ list,
                                                float* __restrict__ rw) {
  int wave = threadIdx.x >> 6, lane = threadIdx.x & 63;
  int b = blockIdx.x * 4 + wave;
  const float* xrow = x + (size_t)b * DD;
  float acc[8];
#pragma unroll
  for (int e = 0; e < 8; ++e) acc[e] = 0.f;
#pragma unroll
  for (int i = 0; i < 4; ++i) {
    int d0 = i * 256 + lane * 4;
    float4 v = *(const float4*)&xrow[d0];
    unsigned lo = (unsigned)f2bf(v.x) | ((unsigned)f2bf(v.y) << 16);
    unsigned hi = (unsigned)f2bf(v.z) | ((unsigned)f2bf(v.w) << 16);
    *(uint2*)&xb[(size_t)b * DD + d0] = make_uint2(lo, hi);
    const float* g0 = &gw[(size_t)d0 * 8];
    float fv[4] = {v.x, v.y, v.z, v.w};
#pragma unroll
    for (int q = 0; q < 4; ++q) {
      float4 ga = *(const float4*)&g0[q * 8];
      float4 gc = *(const float4*)&g0[q * 8 + 4];
      acc[0] += fv[q] * ga.x; acc[1] += fv[q] * ga.y;
      acc[2] += fv[q] * ga.z; acc[3] += fv[q] * ga.w;
      acc[4] += fv[q] * gc.x; acc[5] += fv[q] * gc.y;
      acc[6] += fv[q] * gc.z; acc[7] += fv[q] * gc.w;
    }
  }
#pragma unroll
  for (int off = 32; off > 0; off >>= 1) {
#pragma unroll
    for (int e = 0; e < 8; ++e) acc[e] += __shfl_down(acc[e], off);
  }
  if (lane == 0) {
    float v[8];
#pragma unroll
    for (int e = 0; e < 8; ++e) v[e] = acc[e] + gb[e];
    int i0 = 0;
#pragma unroll
    for (int e = 1; e < 8; ++e) if (v[e] > v[i0]) i0 = e;
    int i1 = (i0 == 0) ? 1 : 0;
#pragma unroll
    for (int e = 0; e < 8; ++e) if (e != i0 && v[e] > v[i1]) i1 = e;
    float e1 = __expf(v[i1] - v[i0]);
    float inv = 1.0f / (1.0f + e1);
    int p0 = atomicAdd(&cnt[i0], 1);
    list[i0 * BT + p0] = 2 * b;     rw[2 * b]     = inv;
    int p1 = atomicAdd(&cnt[i1], 1);
    list[i1 * BT + p1] = 2 * b + 1; rw[2 * b + 1] = e1 * inv;
  }
}

// ---- tile map: (expert, m0, compacted_base) per 256-row tile; ntiles <= 40 ----
__global__ void tilemap_k(const int* __restrict__ cnt, int* __restrict__ tmap,
                          int* __restrict__ ntiles) {
  if (threadIdx.x == 0 && blockIdx.x == 0) {
    int t = 0, basewalk = 0;
    for (int e = 0; e < EE; ++e) {
      int c = cnt[e];
      for (int m0 = 0; m0 < c; m0 += BM) {
        tmap[4 * t] = e; tmap[4 * t + 1] = m0; tmap[4 * t + 2] = basewalk + m0; ++t;
      }
      basewalk += c;
    }
    *ntiles = t;
  }
}

// ------- transpose+convert: src fp32 [E][R][C] -> dst bf16 [E][C][R] -------
__global__ __launch_bounds__(256) void cvt_t_k(const float* __restrict__ src,
                                               unsigned short* __restrict__ dst,
                                               int R, int C) {
  __shared__ unsigned short tile[64][66];
  int e = blockIdx.z;
  const float* s = src + (size_t)e * R * C;
  unsigned short* d = dst + (size_t)e * R * C;
  int r0 = blockIdx.x << 6, c0 = blockIdx.y << 6;
  int t = threadIdx.x;
#pragma unroll
  for (int p = 0; p < 4; ++p) {
    int ch = p * 256 + t;
    int rr = ch >> 4, cc = (ch & 15) << 2;
    float4 v = *(const float4*)&s[(size_t)(r0 + rr) * C + c0 + cc];
    unsigned lo = (unsigned)f2bf(v.x) | ((unsigned)f2bf(v.y) << 16);
    unsigned hi = (unsigned)f2bf(v.z) | ((unsigned)f2bf(v.w) << 16);
    *(uint2*)&tile[rr][cc] = make_uint2(lo, hi);
  }
  __syncthreads();
#pragma unroll
  for (int p = 0; p < 4; ++p) {
    int ch = p * 256 + t;
    int cc = ch >> 4, rr = (ch & 15) << 2;
    unsigned short v0 = tile[rr + 0][cc];
    unsigned short v1 = tile[rr + 1][cc];
    unsigned short v2 = tile[rr + 2][cc];
    unsigned short v3 = tile[rr + 3][cc];
    unsigned lo = (unsigned)v0 | ((unsigned)v1 << 16);
    unsigned hi = (unsigned)v2 | ((unsigned)v3 << 16);
    *(uint2*)&d[(size_t)(c0 + cc) * R + r0 + rr] = make_uint2(lo, hi);
  }
}

// =====================================================================
// GEMM1: hc[base+row] = relu(x[tok] @ w1[e] + b1[e]), compacted layout.
// 256x256 tile, BK=32, ring-4 counted-vmcnt pipeline, XOR chunk swizzle.
// grid: (HH/BN = 16, 40); 512 threads = 8 waves (2M x 4N), wave C = 128x64.
// LDS rows are 64B (BK=32); swizzle chunk ^= (row>>1)&3 makes quarter-wave
// ds_read_b128 2-way (free). global_load_lds writes linearly, so the
// inverse swizzle is applied to the per-lane GLOBAL source address.
// =====================================================================
__global__ __launch_bounds__(512, 2) void gemm1_k(const unsigned short* __restrict__ xb,
                                                  const unsigned short* __restrict__ w1t,
                                                  const float* __restrict__ b1,
                                                  const int* __restrict__ cnt,
                                                  const int* __restrict__ list,
                                                  const int* __restrict__ tmap,
                                                  const int* __restrict__ ntiles,
                                                  unsigned short* __restrict__ hc) {
  int ti = blockIdx.y;
  if (ti >= *ntiles) return;
  int e = tmap[4 * ti], m0 = tmap[4 * ti + 1], base = tmap[4 * ti + 2];
  int cnt_e = cnt[e];
  int n0 = blockIdx.x * BN;

  __shared__ int slotbuf[BM];
  __shared__ __align__(16) unsigned short lds[RING * SLOT_USH];  // 128 KB

  int t = threadIdx.x;
  if (t < BM) {
    int r = m0 + t;
    slotbuf[t] = list[e * BT + (r < cnt_e ? r : 0)];
  }
  __syncthreads();

  int w = t >> 6, l = t & 63, lm = l & 15, lq = l >> 4;
  int wr = w >> 2, wc = w & 3;

  // ---- staging: 4 x 16B per thread per K-tile (A half j=0/1, B half j=0/1) ----
  const unsigned short* aS[2];
  const unsigned short* bS[2];
  int dA[2], dB[2];
#pragma unroll
  for (int j = 0; j < 2; ++j) {
    int row = j * 128 + w * 16 + (l >> 2);               // row within 256-row tile
    int sch = ((l & 3) ^ ((row >> 1) & 3)) * 8;          // inverse-swizzled source chunk
    aS[j] = xb + (size_t)(slotbuf[row] >> 1) * DD + sch;
    bS[j] = w1t + (size_t)e * HH * DD + (size_t)(n0 + row) * DD + sch;
    dA[j] = j * 4096 + w * 512;                          // wave-uniform LDS dest (ushorts)
    dB[j] = A_USH + j * 4096 + w * 512;
  }

  // fragment read offsets (swizzled chunk; (row>>1)&3 reduces to (lm>>1)&3)
  int xc = lq ^ ((lm >> 1) & 3);
  int afo[8], bfo[4];
#pragma unroll
  for (int mi = 0; mi < 8; ++mi) afo[mi] = (wr * 128 + mi * 16 + lm) * BK + xc * 8;
#pragma unroll
  for (int ni = 0; ni < 4; ++ni) bfo[ni] = A_USH + (wc * 64 + ni * 16 + lm) * BK + xc * 8;

  f32x4 acc[8][4];
#pragma unroll
  for (int mi = 0; mi < 8; ++mi)
#pragma unroll
    for (int ni = 0; ni < 4; ++ni) acc[mi][ni] = f32x4{0.f, 0.f, 0.f, 0.f};

  constexpr int NT = DD / BK;  // 32

  // prologue: stage tiles 0..2
#pragma unroll
  for (int p = 0; p < RING - 1; ++p) {
    unsigned short* Lb = lds + p * SLOT_USH;
    glds16(aS[0] + p * BK, Lb + dA[0]);
    glds16(aS[1] + p * BK, Lb + dA[1]);
    glds16(bS[0] + p * BK, Lb + dB[0]);
    glds16(bS[1] + p * BK, Lb + dB[1]);
  }
  asm volatile("s_waitcnt vmcnt(8)" ::: "memory");  // tile 0 landed
  __builtin_amdgcn_s_barrier();
  asm volatile("" ::: "memory");

  for (int tt = 0; tt < NT; ++tt) {
    {  // stage tile tt+3 first (loads in flight earliest); branchless clamped tail
      int ts = tt + 3;
      int ko = (ts < NT ? ts : NT - 1) * BK;
      unsigned short* Lb = lds + (ts & 3) * SLOT_USH;
      glds16(aS[0] + ko, Lb + dA[0]);
      glds16(aS[1] + ko, Lb + dA[1]);
      glds16(bS[0] + ko, Lb + dB[0]);
      glds16(bS[1] + ko, Lb + dB[1]);
    }
    const unsigned short* Lc = lds + (tt & 3) * SLOT_USH;
    bf16x8 af[8], bf[4];
#pragma unroll
    for (int mi = 0; mi < 8; ++mi) af[mi] = *(const bf16x8*)&Lc[afo[mi]];
#pragma unroll
    for (int ni = 0; ni < 4; ++ni) bf[ni] = *(const bf16x8*)&Lc[bfo[ni]];
    __builtin_amdgcn_s_setprio(1);
#pragma unroll
    for (int mi = 0; mi < 8; ++mi)
#pragma unroll
      for (int ni = 0; ni < 4; ++ni)
        acc[mi][ni] = __builtin_amdgcn_mfma_f32_16x16x32_bf16(af[mi], bf[ni], acc[mi][ni], 0, 0, 0);
    __builtin_amdgcn_s_setprio(0);
    asm volatile("s_waitcnt vmcnt(8)" ::: "memory");  // tile tt+1 landed; 2 tiles in flight
    __builtin_amdgcn_s_barrier();
    asm volatile("" ::: "memory");
  }

  // ---- epilogue: drain, then LDS-transpose -> coalesced 16B stores ----
  asm volatile("s_waitcnt vmcnt(0)" ::: "memory");
  __builtin_amdgcn_s_barrier();
  asm volatile("" ::: "memory");
  unsigned short* cb = lds + w * 8192;  // 128x64 bf16 per wave (16 KB), 8x16KB = 128 KB
  float bias[4];
#pragma unroll
  for (int ni = 0; ni < 4; ++ni) bias[ni] = b1[e * HH + n0 + wc * 64 + ni * 16 + lm];
#pragma unroll
  for (int mi = 0; mi < 8; ++mi)
#pragma unroll
    for (int ni = 0; ni < 4; ++ni)
#pragma unroll
      for (int r = 0; r < 4; ++r)
        cb[(mi * 16 + lq * 4 + r) * 64 + ni * 16 + lm] =
            f2bf(fmaxf(acc[mi][ni][r] + bias[ni], 0.0f));
  asm volatile("s_waitcnt lgkmcnt(0)" ::: "memory");  // same-wave LDS write->read
#pragma unroll
  for (int it = 0; it < 16; ++it) {
    int rr = it * 8 + (l >> 3), chk = l & 7;
    int grow = wr * 128 + rr;
    if (m0 + grow < cnt_e) {
      uint4 v = *(const uint4*)&cb[rr * 64 + chk * 8];
      *(uint4*)&hc[(size_t)(base + grow) * HH + n0 + wc * 64 + chk * 8] = v;
    }
  }
}

// =====================================================================
// GEMM2: y[z][slot] = rw*(hc_rows @ w2[e] + b2[e] [z==0]); same pipeline.
// grid: (OO/BN = 4, 40, zsplit)
// =====================================================================
__global__ __launch_bounds__(512, 2) void gemm2_k(const unsigned short* __restrict__ hc,
                                                  const unsigned short* __restrict__ w2t,
                                                  const float* __restrict__ b2,
                                                  const int* __restrict__ cnt,
                                                  const int* __restrict__ list,
                                                  const int* __restrict__ tmap,
                                                  const int* __restrict__ ntiles,
                                                  const float* __restrict__ rw,
                                                  float* __restrict__ ybuf,
                                                  float* __restrict__ out) {
  int ti = blockIdx.y;
  if (ti >= *ntiles) return;
  int e = tmap[4 * ti], m0 = tmap[4 * ti + 1], base = tmap[4 * ti + 2];
  int cnt_e = cnt[e];
  int n0 = blockIdx.x * BN;
  int z = blockIdx.z;
  int ksl = HH / gridDim.z;
  int kb0 = z * ksl;
  int NT = ksl / BK;

  __shared__ int slotbuf[BM];
  __shared__ float rwbuf[BM];
  __shared__ __align__(16) unsigned short lds[RING * SLOT_USH];

  int t = threadIdx.x;
  if (t < BM) {
    int r = m0 + t;
    int s_ = list[e * BT + (r < cnt_e ? r : 0)];
    slotbuf[t] = s_;
    rwbuf[t] = rw[s_];
  }
  __syncthreads();

  int w = t >> 6, l = t & 63, lm = l & 15, lq = l >> 4;
  int wr = w >> 2, wc = w & 3;

  const unsigned short* aS[2];
  const unsigned short* bS[2];
  int dA[2], dB[2];
#pragma unroll
  for (int j = 0; j < 2; ++j) {
    int row = j * 128 + w * 16 + (l >> 2);
    int sch = ((l & 3) ^ ((row >> 1) & 3)) * 8;
    int gr = base + row; if (gr > SLOTS - 1) gr = SLOTS - 1;  // clamp padded rows
    aS[j] = hc + (size_t)gr * HH + kb0 + sch;
    bS[j] = w2t + (size_t)e * OO * HH + (size_t)(n0 + row) * HH + kb0 + sch;
    dA[j] = j * 4096 + w * 512;
    dB[j] = A_USH + j * 4096 + w * 512;
  }

  int xc = lq ^ ((lm >> 1) & 3);
  int afo[8], bfo[4];
#pragma unroll
  for (int mi = 0; mi < 8; ++mi) afo[mi] = (wr * 128 + mi * 16 + lm) * BK + xc * 8;
#pragma unroll
  for (int ni = 0; ni < 4; ++ni) bfo[ni] = A_USH + (wc * 64 + ni * 16 + lm) * BK + xc * 8;

  f32x4 acc[8][4];
#pragma unroll
  for (int mi = 0; mi < 8; ++mi)
#pragma unroll
    for (int ni = 0; ni < 4; ++ni) acc[mi][ni] = f32x4{0.f, 0.f, 0.f, 0.f};

#pragma unroll
  for (int p = 0; p < RING - 1; ++p) {
    unsigned short* Lb = lds + p * SLOT_USH;
    glds16(aS[0] + p * BK, Lb + dA[0]);
    glds16(aS[1] + p * BK, Lb + dA[1]);
    glds16(bS[0] + p * BK, Lb + dB[0]);
    glds16(bS[1] + p * BK, Lb + dB[1]);
  }
  asm volatile("s_waitcnt vmcnt(8)" ::: "memory");
  __builtin_amdgcn_s_barrier();
  asm volatile("" ::: "memory");

  for (int tt = 0; tt < NT; ++tt) {
    {
      int ts = tt + 3;
      int ko = (ts < NT ? ts : NT - 1) * BK;
      unsigned short* Lb = lds + (ts & 3) * SLOT_USH;
      glds16(aS[0] + ko, Lb + dA[0]);
      glds16(aS[1] + ko, Lb + dA[1]);
      glds16(bS[0] + ko, Lb + dB[0]);
      glds16(bS[1] + ko, Lb + dB[1]);
    }
    const unsigned short* Lc = lds + (tt & 3) * SLOT_USH;
    bf16x8 af[8], bf[4];
#pragma unroll
    for (int mi = 0; mi < 8; ++mi) af[mi] = *(const bf16x8*)&Lc[afo[mi]];
#pragma unroll
    for (int ni = 0; ni < 4; ++ni) bf[ni] = *(const bf16x8*)&Lc[bfo[ni]];
    __builtin_amdgcn_s_setprio(1);
#pragma unroll
    for (int mi = 0; mi < 8; ++mi)
#pragma unroll
      for (int ni = 0; ni < 4; ++ni)
        acc[mi][ni] = __builtin_amdgcn_mfma_f32_16x16x32_bf16(af[mi], bf[ni], acc[mi][ni], 0, 0, 0);
    __builtin_amdgcn_s_setprio(0);
    asm volatile("s_waitcnt vmcnt(8)" ::: "memory");
    __builtin_amdgcn_s_barrier();
    asm volatile("" ::: "memory");
  }
  asm volatile("s_waitcnt vmcnt(0)" ::: "memory");  // drain clamped tail loads

  // ---- epilogue: fp32 stores (64B segments, low amplification) ----
  bool addb = (z == 0);
  size_t ybase = (size_t)z * SLOTS;
#pragma unroll
  for (int ni = 0; ni < 4; ++ni) {
    int ncol = n0 + wc * 64 + ni * 16 + lm;
    float bias = addb ? b2[e * OO + ncol] : 0.0f;
#pragma unroll
    for (int mi = 0; mi < 8; ++mi)
#pragma unroll
      for (int r = 0; r < 4; ++r) {
        int lrow = wr * 128 + mi * 16 + lq * 4 + r;
        if (m0 + lrow < cnt_e) {
          float v = (acc[mi][ni][r] + bias) * rwbuf[lrow];
          int slot = slotbuf[lrow];
          if (ybuf) ybuf[(ybase + slot) * OO + ncol] = v;
          else      atomicAdd(&out[(size_t)(slot >> 1) * OO + ncol], v);
        }
      }
  }
}

// ---- combine: out[b] = sum_z (y[z][2b] + y[z][2b+1]) ----
__global__ __launch_bounds__(256) void combine_k(const float* __restrict__ y,
                                                 float* __restrict__ out, int nz) {
  int i = blockIdx.x * 256 + threadIdx.x;        // one float4 of out
  int b = i >> 8, c = i & 255;                   // 256 float4 per row
  f32x4 acc = {0.f, 0.f, 0.f, 0.f};
  for (int z = 0; z < nz; ++z) {
#pragma unroll
    for (int k = 0; k < 2; ++k) {
      const float4 v = *(const float4*)&y[((size_t)z * SLOTS + 2 * b + k) * OO + c * 4];
      acc[0] += v.x; acc[1] += v.y; acc[2] += v.z; acc[3] += v.w;
    }
  }
  *(f32x4*)&out[(size_t)b * OO + c * 4] = acc;
}

extern "C" void kernel_launch(void* const* d_in, const int* in_sizes, int n_in,
                              void* d_out, int out_size, void* d_ws, size_t ws_size,
                              hipStream_t stream) {
  const float* x  = (const float*)d_in[0];
  const float* gw = (const float*)d_in[1];
  const float* gb = (const float*)d_in[2];
  const float* w1 = (const float*)d_in[3];
  const float* b1 = (const float*)d_in[4];
  const float* w2 = (const float*)d_in[5];
  const float* b2 = (const float*)d_in[6];
  float* out = (float*)d_out;
  char* ws = (char*)d_ws;

  // ws layout
  int*            cnt    = (int*)(ws);                          // 32 B
  int*            ntiles = (int*)(ws + 64);
  int*            tmap   = (int*)(ws + 128);                    // 40*16 B
  float*          rw     = (float*)(ws + 4096);                 // 32 KB
  int*            list   = (int*)(ws + (64u << 10));            // 128 KB
  unsigned short* xb     = (unsigned short*)(ws + (1u  << 20)); // 8 MB
  unsigned short* wt     = (unsigned short*)(ws + (9u  << 20)); // 64 MB (w1t, then w2t)
  unsigned short* hc     = (unsigned short*)(ws + (73u << 20)); // 64 MB + 1 MB slack
  float*          ybuf   = (float*)(ws + (138u << 20));         // up to 64 MB

  size_t need_min = (138u << 20);
  if (ws_size < need_min) return;
  int zsplit;
  float* ypass;
  if (ws_size >= (138u << 20) + (size_t)2 * SLOTS * OO * 4) { zsplit = 2; ypass = ybuf; }
  else if (ws_size >= (138u << 20) + (size_t)SLOTS * OO * 4) { zsplit = 1; ypass = ybuf; }
  else { zsplit = 2; ypass = nullptr; }

  hipMemsetAsync(cnt, 0, 64, stream);
  if (!ypass) hipMemsetAsync(out, 0, (size_t)BT * OO * sizeof(float), stream);

  router_k<<<BT / 4, 256, 0, stream>>>(x, gw, gb, xb, cnt, list, rw);
  tilemap_k<<<1, 64, 0, stream>>>(cnt, tmap, ntiles);
  cvt_t_k<<<dim3(DD / 64, HH / 64, EE), 256, 0, stream>>>(w1, wt, DD, HH);
  gemm1_k<<<dim3(HH / BN, MAXT), 512, 0, stream>>>(xb, wt, b1, cnt, list, tmap, ntiles, hc);
  cvt_t_k<<<dim3(HH / 64, OO / 64, EE), 256, 0, stream>>>(w2, wt, HH, OO);
  gemm2_k<<<dim3(OO / BN, MAXT, zsplit), 512, 0, stream>>>(hc, wt, b2, cnt, list, tmap, ntiles, rw, ypass, out);
  if (ypass)
    combine_k<<<BT * OO / 1024, 256, 0, stream>>>(ybuf, out, zsplit);
}

// Round 4
// 650.234 us; speedup vs baseline: 1.1286x; 1.1286x over previous
//
#include <hip/hip_runtime.h>
#include <stdint.h>

typedef short bf16x8 __attribute__((ext_vector_type(8)));
typedef float f32x4  __attribute__((ext_vector_type(4)));

constexpr int BT = 4096;   // tokens
constexpr int DD = 1024;   // model dim
constexpr int OO = 1024;   // output dim
constexpr int EE = 8;      // experts
constexpr int HH = 4096;   // hidden dim
constexpr int SLOTS = 2 * BT;  // 8192

// ---- GEMM geometry: 128x128 tile, BK=32, ring-3, 3 blocks/CU ----
constexpr int BM = 128, BN = 128, BK = 32;
constexpr int A_USH = BM * BK;             // 4096 ushorts (8 KB)
constexpr int SLOT_USH = (BM + BN) * BK;   // 8192 ushorts (16 KB)
constexpr int MAXT = 72;                   // max 128-row m-tiles (worst case 71)
constexpr int G1_BLKS = 32 * MAXT;         // gemm1 slots in fusedB grid

__device__ __forceinline__ unsigned short f2bf(float f) {
  unsigned u = __float_as_uint(f);
  u += 0x7fffu + ((u >> 16) & 1u);   // round-to-nearest-even
  return (unsigned short)(u >> 16);
}

// async 16B global->LDS. LDS dest is wave-uniform base; HW adds lane*16.
__device__ __forceinline__ void glds16(const unsigned short* g, unsigned short* l) {
  __builtin_amdgcn_global_load_lds(
      (const __attribute__((address_space(1))) void*)g,
      (__attribute__((address_space(3))) void*)l, 16, 0, 0);
}

// ------- transpose+convert body: src fp32 [e][R][C] -> dst bf16 [e][C][R] -------
__device__ __forceinline__ void cvt_body(const float* __restrict__ src,
                                         unsigned short* __restrict__ dst,
                                         int R, int C, int e, int r0, int c0, int t,
                                         unsigned short (*tile)[66]) {
  const float* s = src + (size_t)e * R * C;
  unsigned short* d = dst + (size_t)e * R * C;
#pragma unroll
  for (int p = 0; p < 4; ++p) {
    int ch = p * 256 + t;
    int rr = ch >> 4, cc = (ch & 15) << 2;
    float4 v = *(const float4*)&s[(size_t)(r0 + rr) * C + c0 + cc];
    unsigned lo = (unsigned)f2bf(v.x) | ((unsigned)f2bf(v.y) << 16);
    unsigned hi = (unsigned)f2bf(v.z) | ((unsigned)f2bf(v.w) << 16);
    *(uint2*)&tile[rr][cc] = make_uint2(lo, hi);
  }
  __syncthreads();
#pragma unroll
  for (int p = 0; p < 4; ++p) {
    int ch = p * 256 + t;
    int cc = ch >> 4, rr = (ch & 15) << 2;
    unsigned short v0 = tile[rr + 0][cc];
    unsigned short v1 = tile[rr + 1][cc];
    unsigned short v2 = tile[rr + 2][cc];
    unsigned short v3 = tile[rr + 3][cc];
    unsigned lo = (unsigned)v0 | ((unsigned)v1 << 16);
    unsigned hi = (unsigned)v2 | ((unsigned)v3 << 16);
    *(uint2*)&d[(size_t)(c0 + cc) * R + r0 + rr] = make_uint2(lo, hi);
  }
}

// ---------- fusedA: router (blocks 0..1023) + cvt(w1) (blocks 1024..9215) ----------
__global__ __launch_bounds__(256) void fusedA_k(const float* __restrict__ x,
                                                const float* __restrict__ gw,
                                                const float* __restrict__ gb,
                                                const float* __restrict__ w1,
                                                unsigned short* __restrict__ xb,
                                                int* __restrict__ cnt,
                                                int* __restrict__ list,
                                                float* __restrict__ rw,
                                                unsigned short* __restrict__ w1t) {
  __shared__ unsigned short tile[64][66];
  int bid = blockIdx.x;
  if (bid >= 1024) {  // cvt(w1): fp32 [e][1024][4096] -> bf16 [e][4096][1024]
    int idx = bid - 1024;
    int e = idx >> 10, rem = idx & 1023;
    int r0 = (rem & 15) << 6, c0 = (rem >> 4) << 6;
    cvt_body(w1, w1t, DD, HH, e, r0, c0, threadIdx.x, tile);
    return;
  }
  int wave = threadIdx.x >> 6, lane = threadIdx.x & 63;
  int b = bid * 4 + wave;
  const float* xrow = x + (size_t)b * DD;
  float acc[8];
#pragma unroll
  for (int e = 0; e < 8; ++e) acc[e] = 0.f;
#pragma unroll
  for (int i = 0; i < 4; ++i) {
    int d0 = i * 256 + lane * 4;
    float4 v = *(const float4*)&xrow[d0];
    unsigned lo = (unsigned)f2bf(v.x) | ((unsigned)f2bf(v.y) << 16);
    unsigned hi = (unsigned)f2bf(v.z) | ((unsigned)f2bf(v.w) << 16);
    *(uint2*)&xb[(size_t)b * DD + d0] = make_uint2(lo, hi);
    const float* g0 = &gw[(size_t)d0 * 8];
    float fv[4] = {v.x, v.y, v.z, v.w};
#pragma unroll
    for (int q = 0; q < 4; ++q) {
      float4 ga = *(const float4*)&g0[q * 8];
      float4 gc = *(const float4*)&g0[q * 8 + 4];
      acc[0] += fv[q] * ga.x; acc[1] += fv[q] * ga.y;
      acc[2] += fv[q] * ga.z; acc[3] += fv[q] * ga.w;
      acc[4] += fv[q] * gc.x; acc[5] += fv[q] * gc.y;
      acc[6] += fv[q] * gc.z; acc[7] += fv[q] * gc.w;
    }
  }
#pragma unroll
  for (int off = 32; off > 0; off >>= 1) {
#pragma unroll
    for (int e = 0; e < 8; ++e) acc[e] += __shfl_down(acc[e], off);
  }
  if (lane == 0) {
    float v[8];
#pragma unroll
    for (int e = 0; e < 8; ++e) v[e] = acc[e] + gb[e];
    int i0 = 0;
#pragma unroll
    for (int e = 1; e < 8; ++e) if (v[e] > v[i0]) i0 = e;
    int i1 = (i0 == 0) ? 1 : 0;
#pragma unroll
    for (int e = 0; e < 8; ++e) if (e != i0 && v[e] > v[i1]) i1 = e;
    float e1 = __expf(v[i1] - v[i0]);
    float inv = 1.0f / (1.0f + e1);
    int p0 = atomicAdd(&cnt[i0], 1);
    list[i0 * BT + p0] = 2 * b;     rw[2 * b]     = inv;
    int p1 = atomicAdd(&cnt[i1], 1);
    list[i1 * BT + p1] = 2 * b + 1; rw[2 * b + 1] = e1 * inv;
  }
}

// ---- tile map: (expert, m0, compacted_base) per 128-row tile ----
__global__ void tilemap_k(const int* __restrict__ cnt, int* __restrict__ tmap,
                          int* __restrict__ ntiles) {
  if (threadIdx.x == 0 && blockIdx.x == 0) {
    int t = 0, basewalk = 0;
    for (int e = 0; e < EE; ++e) {
      int c = cnt[e];
      for (int m0 = 0; m0 < c; m0 += BM) {
        tmap[4 * t] = e; tmap[4 * t + 1] = m0; tmap[4 * t + 2] = basewalk + m0; ++t;
      }
      basewalk += c;
    }
    *ntiles = t;
  }
}

// standalone cvt (tight-ws fallback only)
__global__ __launch_bounds__(256) void cvt_t_k(const float* __restrict__ src,
                                               unsigned short* __restrict__ dst,
                                               int R, int C) {
  __shared__ unsigned short tile[64][66];
  cvt_body(src, dst, R, C, blockIdx.z, blockIdx.x << 6, blockIdx.y << 6,
           threadIdx.x, tile);
}

// =====================================================================
// fusedB: GEMM1 (blocks 0..G1_BLKS-1) + cvt(w2) (blocks G1_BLKS..+8191).
// GEMM1: hc[base+row] = relu(x[tok] @ w1[e] + b1[e]), compacted layout.
// 128x128 tile, BK=32, ring-3 counted-vmcnt, XOR chunk swizzle,
// 256 threads = 4 waves (2M x 2N), 48KB LDS -> 3 blocks/CU.
// =====================================================================
__global__ __launch_bounds__(256, 3) void fusedB_k(const unsigned short* __restrict__ xb,
                                                   const unsigned short* __restrict__ w1t,
                                                   const float* __restrict__ b1,
                                                   const int* __restrict__ cnt,
                                                   const int* __restrict__ list,
                                                   const int* __restrict__ tmap,
                                                   const int* __restrict__ ntiles,
                                                   unsigned short* __restrict__ hc,
                                                   const float* __restrict__ w2,
                                                   unsigned short* __restrict__ w2t) {
  __shared__ __align__(16) unsigned short lds[3 * SLOT_USH];  // 48 KB
  __shared__ int slotbuf[BM];
  int bid = blockIdx.x;
  if (bid >= G1_BLKS) {  // cvt(w2): fp32 [e][4096][1024] -> bf16 [e][1024][4096]
    int idx = bid - G1_BLKS;
    int e = idx >> 10, rem = idx & 1023;
    int r0 = (rem & 63) << 6, c0 = (rem >> 6) << 6;
    cvt_body(w2, w2t, HH, OO, e, r0, c0, threadIdx.x,
             (unsigned short (*)[66])lds);
    return;
  }
  int ti = bid >> 5;
  if (ti >= *ntiles) return;
  int e = tmap[4 * ti], m0 = tmap[4 * ti + 1], base = tmap[4 * ti + 2];
  int cnt_e = cnt[e];
  int n0 = (bid & 31) * BN;

  int t = threadIdx.x;
  if (t < BM) {
    int r = m0 + t;
    slotbuf[t] = list[e * BT + (r < cnt_e ? r : 0)];
  }
  __syncthreads();

  int w = t >> 6, l = t & 63, lm = l & 15, lq = l >> 4;
  int wm = (w >> 1) * 64, wn = (w & 1) * 64;

  // staging: 4 x 16B per thread per K-tile (A j=0/1, B j=0/1); wave w covers
  // rows [w*32, w*32+32). Inverse swizzle on the GLOBAL source chunk.
  const unsigned short* aS[2];
  const unsigned short* bS[2];
  int dA[2], dB[2];
#pragma unroll
  for (int j = 0; j < 2; ++j) {
    int row = w * 32 + j * 16 + (l >> 2);
    int sch = ((l & 3) ^ ((row >> 1) & 3)) * 8;
    aS[j] = xb + (size_t)(slotbuf[row] >> 1) * DD + sch;
    bS[j] = w1t + (size_t)e * HH * DD + (size_t)(n0 + row) * DD + sch;
    dA[j] = w * 1024 + j * 512;
    dB[j] = A_USH + w * 1024 + j * 512;
  }

  // fragment read offsets with matching swizzle (2-way -> conflict-free)
  int xs = (lq ^ ((lm >> 1) & 3)) * 8;
  int afo[4], bfo[4];
#pragma unroll
  for (int mi = 0; mi < 4; ++mi) afo[mi] = (wm + mi * 16 + lm) * BK + xs;
#pragma unroll
  for (int ni = 0; ni < 4; ++ni) bfo[ni] = A_USH + (wn + ni * 16 + lm) * BK + xs;

  f32x4 acc[4][4];
#pragma unroll
  for (int mi = 0; mi < 4; ++mi)
#pragma unroll
    for (int ni = 0; ni < 4; ++ni) acc[mi][ni] = f32x4{0.f, 0.f, 0.f, 0.f};

  constexpr int NT = DD / BK;  // 32

  // ring-3 prologue: stage tiles 0 (slot0) and 1 (slot1)
#pragma unroll
  for (int p = 0; p < 2; ++p) {
    unsigned short* Lb = lds + p * SLOT_USH;
    glds16(aS[0] + p * BK, Lb + dA[0]);
    glds16(aS[1] + p * BK, Lb + dA[1]);
    glds16(bS[0] + p * BK, Lb + dB[0]);
    glds16(bS[1] + p * BK, Lb + dB[1]);
  }
  asm volatile("s_waitcnt vmcnt(4)" ::: "memory");  // tile 0 landed
  __builtin_amdgcn_s_barrier();
  asm volatile("" ::: "memory");

  int sc = 0, ss = 2;
  for (int tt = 0; tt < NT; ++tt) {
    {  // stage tile tt+2 (branchless clamped tail keeps vmcnt exact)
      int ts = tt + 2;
      int ko = (ts < NT ? ts : NT - 1) * BK;
      unsigned short* Lb = lds + ss * SLOT_USH;
      glds16(aS[0] + ko, Lb + dA[0]);
      glds16(aS[1] + ko, Lb + dA[1]);
      glds16(bS[0] + ko, Lb + dB[0]);
      glds16(bS[1] + ko, Lb + dB[1]);
    }
    const unsigned short* Lc = lds + sc * SLOT_USH;
    bf16x8 af[4], bf[4];
#pragma unroll
    for (int mi = 0; mi < 4; ++mi) af[mi] = *(const bf16x8*)&Lc[afo[mi]];
#pragma unroll
    for (int ni = 0; ni < 4; ++ni) bf[ni] = *(const bf16x8*)&Lc[bfo[ni]];
    __builtin_amdgcn_s_setprio(1);
#pragma unroll
    for (int mi = 0; mi < 4; ++mi)
#pragma unroll
      for (int ni = 0; ni < 4; ++ni)
        acc[mi][ni] = __builtin_amdgcn_mfma_f32_16x16x32_bf16(af[mi], bf[ni], acc[mi][ni], 0, 0, 0);
    __builtin_amdgcn_s_setprio(0);
    asm volatile("s_waitcnt vmcnt(4)" ::: "memory");  // tile tt+1 landed
    __builtin_amdgcn_s_barrier();
    asm volatile("" ::: "memory");
    if (++sc == 3) sc = 0;
    if (++ss == 3) ss = 0;
  }

  // epilogue: drain, then LDS-transpose -> coalesced 16B stores
  asm volatile("s_waitcnt vmcnt(0)" ::: "memory");
  __builtin_amdgcn_s_barrier();
  asm volatile("" ::: "memory");
  unsigned short* cb = lds + w * 4096;  // 64x64 bf16 per wave (8 KB)
  float bias[4];
#pragma unroll
  for (int ni = 0; ni < 4; ++ni) bias[ni] = b1[e * HH + n0 + wn + ni * 16 + lm];
#pragma unroll
  for (int mi = 0; mi < 4; ++mi)
#pragma unroll
    for (int ni = 0; ni < 4; ++ni)
#pragma unroll
      for (int r = 0; r < 4; ++r)
        cb[(mi * 16 + lq * 4 + r) * 64 + ni * 16 + lm] =
            f2bf(fmaxf(acc[mi][ni][r] + bias[ni], 0.0f));
  asm volatile("s_waitcnt lgkmcnt(0)" ::: "memory");
#pragma unroll
  for (int it = 0; it < 8; ++it) {
    int rr = it * 8 + (l >> 3), chk = l & 7;
    int grow = wm + rr;
    if (m0 + grow < cnt_e) {
      uint4 v = *(const uint4*)&cb[rr * 64 + chk * 8];
      *(uint4*)&hc[(size_t)(base + grow) * HH + n0 + wn + chk * 8] = v;
    }
  }
}

// =====================================================================
// GEMM2: y[z][slot] = rw*(hc_rows @ w2[e] + b2[e] [z==0]); same pipeline.
// grid: (OO/BN = 8, MAXT, 2)
// =====================================================================
__global__ __launch_bounds__(256, 3) void gemm2_k(const unsigned short* __restrict__ hc,
                                                  const unsigned short* __restrict__ w2t,
                                                  const float* __restrict__ b2,
                                                  const int* __restrict__ cnt,
                                                  const int* __restrict__ list,
                                                  const int* __restrict__ tmap,
                                                  const int* __restrict__ ntiles,
                                                  const float* __restrict__ rw,
                                                  float* __restrict__ ybuf,
                                                  float* __restrict__ out) {
  int ti = blockIdx.y;
  if (ti >= *ntiles) return;
  int e = tmap[4 * ti], m0 = tmap[4 * ti + 1], base = tmap[4 * ti + 2];
  int cnt_e = cnt[e];
  int n0 = blockIdx.x * BN;
  int z = blockIdx.z;
  int kb0 = z * (HH / 2);
  constexpr int NT = (HH / 2) / BK;  // 64

  __shared__ __align__(16) unsigned short lds[3 * SLOT_USH];
  __shared__ int slotbuf[BM];
  __shared__ float rwbuf[BM];

  int t = threadIdx.x;
  if (t < BM) {
    int r = m0 + t;
    int s_ = list[e * BT + (r < cnt_e ? r : 0)];
    slotbuf[t] = s_;
    rwbuf[t] = rw[s_];
  }
  __syncthreads();

  int w = t >> 6, l = t & 63, lm = l & 15, lq = l >> 4;
  int wm = (w >> 1) * 64, wn = (w & 1) * 64;

  const unsigned short* aS[2];
  const unsigned short* bS[2];
  int dA[2], dB[2];
#pragma unroll
  for (int j = 0; j < 2; ++j) {
    int row = w * 32 + j * 16 + (l >> 2);
    int sch = ((l & 3) ^ ((row >> 1) & 3)) * 8;
    int gr = base + row; if (gr > SLOTS - 1) gr = SLOTS - 1;  // clamp padded rows
    aS[j] = hc + (size_t)gr * HH + kb0 + sch;
    bS[j] = w2t + (size_t)e * OO * HH + (size_t)(n0 + row) * HH + kb0 + sch;
    dA[j] = w * 1024 + j * 512;
    dB[j] = A_USH + w * 1024 + j * 512;
  }

  int xs = (lq ^ ((lm >> 1) & 3)) * 8;
  int afo[4], bfo[4];
#pragma unroll
  for (int mi = 0; mi < 4; ++mi) afo[mi] = (wm + mi * 16 + lm) * BK + xs;
#pragma unroll
  for (int ni = 0; ni < 4; ++ni) bfo[ni] = A_USH + (wn + ni * 16 + lm) * BK + xs;

  f32x4 acc[4][4];
#pragma unroll
  for (int mi = 0; mi < 4; ++mi)
#pragma unroll
    for (int ni = 0; ni < 4; ++ni) acc[mi][ni] = f32x4{0.f, 0.f, 0.f, 0.f};

#pragma unroll
  for (int p = 0; p < 2; ++p) {
    unsigned short* Lb = lds + p * SLOT_USH;
    glds16(aS[0] + p * BK, Lb + dA[0]);
    glds16(aS[1] + p * BK, Lb + dA[1]);
    glds16(bS[0] + p * BK, Lb + dB[0]);
    glds16(bS[1] + p * BK, Lb + dB[1]);
  }
  asm volatile("s_waitcnt vmcnt(4)" ::: "memory");
  __builtin_amdgcn_s_barrier();
  asm volatile("" ::: "memory");

  int sc = 0, ss = 2;
  for (int tt = 0; tt < NT; ++tt) {
    {
      int ts = tt + 2;
      int ko = (ts < NT ? ts : NT - 1) * BK;
      unsigned short* Lb = lds + ss * SLOT_USH;
      glds16(aS[0] + ko, Lb + dA[0]);
      glds16(aS[1] + ko, Lb + dA[1]);
      glds16(bS[0] + ko, Lb + dB[0]);
      glds16(bS[1] + ko, Lb + dB[1]);
    }
    const unsigned short* Lc = lds + sc * SLOT_USH;
    bf16x8 af[4], bf[4];
#pragma unroll
    for (int mi = 0; mi < 4; ++mi) af[mi] = *(const bf16x8*)&Lc[afo[mi]];
#pragma unroll
    for (int ni = 0; ni < 4; ++ni) bf[ni] = *(const bf16x8*)&Lc[bfo[ni]];
    __builtin_amdgcn_s_setprio(1);
#pragma unroll
    for (int mi = 0; mi < 4; ++mi)
#pragma unroll
      for (int ni = 0; ni < 4; ++ni)
        acc[mi][ni] = __builtin_amdgcn_mfma_f32_16x16x32_bf16(af[mi], bf[ni], acc[mi][ni], 0, 0, 0);
    __builtin_amdgcn_s_setprio(0);
    asm volatile("s_waitcnt vmcnt(4)" ::: "memory");
    __builtin_amdgcn_s_barrier();
    asm volatile("" ::: "memory");
    if (++sc == 3) sc = 0;
    if (++ss == 3) ss = 0;
  }
  asm volatile("s_waitcnt vmcnt(0)" ::: "memory");  // drain clamped tail loads

  bool addb = (z == 0);
  size_t ybase = (size_t)z * SLOTS;
#pragma unroll
  for (int ni = 0; ni < 4; ++ni) {
    int ncol = n0 + wn + ni * 16 + lm;
    float bias = addb ? b2[e * OO + ncol] : 0.0f;
#pragma unroll
    for (int mi = 0; mi < 4; ++mi)
#pragma unroll
      for (int r = 0; r < 4; ++r) {
        int lrow = wm + mi * 16 + lq * 4 + r;
        if (m0 + lrow < cnt_e) {
          float v = (acc[mi][ni][r] + bias) * rwbuf[lrow];
          int slot = slotbuf[lrow];
          if (ybuf) ybuf[(ybase + slot) * OO + ncol] = v;
          else      atomicAdd(&out[(size_t)(slot >> 1) * OO + ncol], v);
        }
      }
  }
}

// ---- combine: out[b] = sum_z (y[z][2b] + y[z][2b+1]) ----
__global__ __launch_bounds__(256) void combine_k(const float* __restrict__ y,
                                                 float* __restrict__ out, int nz) {
  int i = blockIdx.x * 256 + threadIdx.x;
  int b = i >> 8, c = i & 255;
  f32x4 acc = {0.f, 0.f, 0.f, 0.f};
  for (int z = 0; z < nz; ++z) {
#pragma unroll
    for (int k = 0; k < 2; ++k) {
      const float4 v = *(const float4*)&y[((size_t)z * SLOTS + 2 * b + k) * OO + c * 4];
      acc[0] += v.x; acc[1] += v.y; acc[2] += v.z; acc[3] += v.w;
    }
  }
  *(f32x4*)&out[(size_t)b * OO + c * 4] = acc;
}

extern "C" void kernel_launch(void* const* d_in, const int* in_sizes, int n_in,
                              void* d_out, int out_size, void* d_ws, size_t ws_size,
                              hipStream_t stream) {
  const float* x  = (const float*)d_in[0];
  const float* gw = (const float*)d_in[1];
  const float* gb = (const float*)d_in[2];
  const float* w1 = (const float*)d_in[3];
  const float* b1 = (const float*)d_in[4];
  const float* w2 = (const float*)d_in[5];
  const float* b2 = (const float*)d_in[6];
  float* out = (float*)d_out;
  char* ws = (char*)d_ws;

  int*            cnt    = (int*)(ws);                          // 32 B
  int*            ntiles = (int*)(ws + 64);
  int*            tmap   = (int*)(ws + 128);                    // 72*16 B
  float*          rw     = (float*)(ws + 4096);                 // 32 KB
  int*            list   = (int*)(ws + (64u << 10));            // 128 KB
  unsigned short* xb     = (unsigned short*)(ws + (1u  << 20)); // 8 MB
  unsigned short* w1t    = (unsigned short*)(ws + (9u  << 20)); // 64 MB

  bool roomy = ws_size >= (201u << 20);
  hipMemsetAsync(cnt, 0, 64, stream);

  if (roomy) {
    // w2t gets its own region so cvt(w2) overlaps gemm1; ybuf aliases w1t
    // (w1t dead after fusedB; ybuf live only gemm2->combine).
    unsigned short* w2t = (unsigned short*)(ws + (73u  << 20));  // 64 MB
    unsigned short* hc  = (unsigned short*)(ws + (137u << 20));  // 64 MB
    float*          ybuf = (float*)(ws + (9u << 20));            // alias w1t

    fusedA_k<<<1024 + 8192, 256, 0, stream>>>(x, gw, gb, w1, xb, cnt, list, rw, w1t);
    tilemap_k<<<1, 64, 0, stream>>>(cnt, tmap, ntiles);
    fusedB_k<<<G1_BLKS + 8192, 256, 0, stream>>>(xb, w1t, b1, cnt, list, tmap, ntiles,
                                                 hc, w2, w2t);
    gemm2_k<<<dim3(OO / BN, MAXT, 2), 256, 0, stream>>>(hc, w2t, b2, cnt, list, tmap,
                                                        ntiles, rw, ybuf, out);
    combine_k<<<BT * OO / 1024, 256, 0, stream>>>(ybuf, out, 2);
  } else {
    // tight fallback: serial cvt(w2) overwrites w1t region; atomic gemm2.
    if (ws_size < (137u << 20)) return;
    unsigned short* w2t = w1t;
    unsigned short* hc  = (unsigned short*)(ws + (73u << 20));
    hipMemsetAsync(out, 0, (size_t)BT * OO * sizeof(float), stream);
    fusedA_k<<<1024 + 8192, 256, 0, stream>>>(x, gw, gb, w1, xb, cnt, list, rw, w1t);
    tilemap_k<<<1, 64, 0, stream>>>(cnt, tmap, ntiles);
    fusedB_k<<<G1_BLKS, 256, 0, stream>>>(xb, w1t, b1, cnt, list, tmap, ntiles,
                                          hc, w2, w2t);
    cvt_t_k<<<dim3(HH / 64, OO / 64, EE), 256, 0, stream>>>(w2, w2t, HH, OO);
    gemm2_k<<<dim3(OO / BN, MAXT, 2), 256, 0, stream>>>(hc, w2t, b2, cnt, list, tmap,
                                                        ntiles, rw, nullptr, out);
  }
}